// Round 8
// baseline (193.861 us; speedup 1.0000x reference)
//
#include <hip/hip_runtime.h>
#include <hip/hip_bf16.h>

typedef __hip_bfloat16 bf16;
typedef __attribute__((ext_vector_type(8))) short short8v;   // 8 bf16 (4 VGPRs)
typedef __attribute__((ext_vector_type(4))) float float4v;   // MFMA C/D frag
typedef __attribute__((ext_vector_type(4))) unsigned int uint4v; // NT-store safe

// Problem constants
#define UU 1024
#define BB 8
#define DD 512
#define HH 8
#define HD 64
#define RR 64
#define SS 16
#define MM 15
#define QQ 1104   // R + U + S
#define KVL 1103  // M + R + U
#define PEL 2047
#define NU 1536   // fused QKV output width
#define MU 8952   // union rows (15+64+1024+16)*8

#define AS1 __attribute__((address_space(1)))
#define AS3 __attribute__((address_space(3)))

__device__ __forceinline__ float lo16(unsigned u) { return __uint_as_float(u << 16); }
__device__ __forceinline__ float hi16(unsigned u) { return __uint_as_float(u & 0xffff0000u); }
__device__ __forceinline__ unsigned pk2(float a, float b) {
  unsigned short x = __builtin_bit_cast(unsigned short, __float2bfloat16(a));
  unsigned short y = __builtin_bit_cast(unsigned short, __float2bfloat16(b));
  return (unsigned)x | ((unsigned)y << 16);
}

// r5/r6 COUNTER FACT: consumers get ~ZERO L2 hits on producer-written data
// (gemm8 FETCH 12.5MB = all of XU+Wcat; attn FETCH 27MB = all of qkv) --
// per-XCD L2s don't share; dirty-remote lines are the worst path. So the
// big streamed intermediates (XU, qkv) are written NT (clean HBM handoff)
// while small hot data (weights) and attn-rows stay cached.
// r3 LESSON: NT on attn-rows starved outproj; d_out NT is fine.
// r4 LESSON: 47.9KB V-late LDS overlay NaN'd twice; attn keeps 64KB layout.
// r7 LESSON: __builtin_nontemporal_store rejects HIP's uint4 class type --
// must bit_cast to a clang ext_vector (uint4v) first.
__device__ __forceinline__ void nt_st_bf16(bf16* p, float v) {
  bf16 t = __float2bfloat16(v);
  __builtin_nontemporal_store(__builtin_bit_cast(short, t), (short*)p);
}
__device__ __forceinline__ void nt_st_f32(float* p, float v) {
  __builtin_nontemporal_store(v, p);
}
__device__ __forceinline__ void nt_st_u4(void* p, uint4 v) {
  __builtin_nontemporal_store(__builtin_bit_cast(uint4v, v), (uint4v*)p);
}

// ---- fused canonicalization + in-block dtype detection ----
// Copies into workspace (even for bf16): fp32->bf16 narrowing halves the
// GEMM's read traffic (r6-vs-r8 measured keeper). XU/posec segments (s<5)
// use NT stores (read-once by gemm8, cross-XCD -> HBM anyway); weights
// (s>=5, small+hot) stay cached.
struct PackDesc {
  const void* src[16];
  unsigned int srcoff[16];
  unsigned int dstoff[16];
  unsigned int cum[17];   // cumulative 8-element chunks
};

__global__ __launch_bounds__(256) void pack_all(PackDesc d, bf16* base,
                                                const void* __restrict__ probe,
                                                int* __restrict__ flagout,
                                                int nchunks) {
  __shared__ int wsum[4];
  const unsigned short* p = (const unsigned short*)probe;
  int big = 0;
  for (int i = threadIdx.x; i < 4096; i += 256)
    big += (((p[i] >> 7) & 0xFF) >= 137) ? 1 : 0;
  #pragma unroll
  for (int off = 32; off; off >>= 1) big += __shfl_down(big, off);
  if ((threadIdx.x & 63) == 0) wsum[threadIdx.x >> 6] = big;
  __syncthreads();
  const int flag = (wsum[0] + wsum[1] + wsum[2] + wsum[3] < 16) ? 1 : 0;
  if (threadIdx.x == 0 && blockIdx.x == 0) *flagout = flag;

  int g = blockIdx.x * 256 + threadIdx.x;
  if (g >= nchunks) return;
  int s = 0;
  #pragma unroll
  for (int i = 1; i < 17; ++i) s += (g >= d.cum[i]) ? 1 : 0;
  unsigned local = (g - d.cum[s]) * 8u;
  bf16* dst = base + d.dstoff[s] + local;
  uint4 o;
  if (flag) {
    o = *(const uint4*)((const bf16*)d.src[s] + d.srcoff[s] + local);
  } else {
    const float* fp = (const float*)d.src[s] + d.srcoff[s] + local;
    o.x = pk2(fp[0], fp[1]);
    o.y = pk2(fp[2], fp[3]);
    o.z = pk2(fp[4], fp[5]);
    o.w = pk2(fp[6], fp[7]);
  }
  if (s < 5) nt_st_u4(dst, o);     // XU union + posec: streamed, read-once
  else       *(uint4*)dst = o;     // weights/biases: small, keep cached
}

// ---- MFMA GEMM, 64x128 tile, BK=128, XOR-swizzled LDS, 48KB -> 3 blocks/CU.
// Out-projection only (writes d_out) -> NT epilogue.
struct GemmP {
  const bf16* X; const bf16* W; const bf16* bias; void* out;
  int M, N, K; const int* outf;
};

__global__ __launch_bounds__(256, 3) void gemm_dual(GemmP g0, GemmP g1, int ysplit) {
  __shared__ bf16 As[64 * 128];
  __shared__ bf16 Bs[128 * 128];
  GemmP g; int bm, bn;
  if ((int)blockIdx.y < ysplit) {
    g = g0;
    int bi = (int)blockIdx.y * (int)gridDim.x + (int)blockIdx.x;
    int nbn = g0.N >> 7;
    int j = bi >> 3;
    int bmi = (bi & 7) + (j / nbn) * 8;
    int bni = j % nbn;
    if (bmi >= ((g0.M + 63) >> 6)) return;
    bm = bmi * 64; bn = bni * 128;
  } else {
    g = g1;
    int nt = g1.N >> 7;
    int bi = ((int)blockIdx.y - ysplit) * gridDim.x + blockIdx.x;
    if (bi >= ((g1.M + 63) >> 6) * nt) return;
    bm = (bi / nt) * 64; bn = (bi % nt) * 128;
  }
  const int tid = threadIdx.x;
  const int lane = tid & 63, wv = tid >> 6;
  const int wr = wv >> 1, wc = wv & 1;
  const int l4 = lane >> 4;            // row within 4-row staging group
  const int lb = lane & 15;            // 16B block within 256B row
  const int quad = lane >> 4, l15 = lane & 15;

  float4v acc[2][4] = {};

  for (int kb = 0; kb < g.K; kb += 128) {
    // stage A: 64 rows x 128 cols (16 KB)
    #pragma unroll
    for (int i = 0; i < 4; ++i) {
      int r = wv * 16 + i * 4 + l4;
      int gm = bm + r; if (gm > g.M - 1) gm = g.M - 1;
      const bf16* src = g.X + (size_t)gm * g.K + kb + ((lb ^ (r & 15)) * 8);
      __builtin_amdgcn_global_load_lds((const AS1 void*)src,
                                       (AS3 void*)&As[(wv * 16 + i * 4) * 128], 16, 0, 0);
    }
    // stage B: 128 rows x 128 cols (32 KB)
    #pragma unroll
    for (int i = 0; i < 8; ++i) {
      int r = wv * 32 + i * 4 + l4;
      int gn = bn + r; if (gn > g.N - 1) gn = g.N - 1;
      const bf16* src = g.W + (size_t)gn * g.K + kb + ((lb ^ (r & 15)) * 8);
      __builtin_amdgcn_global_load_lds((const AS1 void*)src,
                                       (AS3 void*)&Bs[(wv * 32 + i * 4) * 128], 16, 0, 0);
    }
    __syncthreads();
    #pragma unroll
    for (int ki = 0; ki < 4; ++ki) {
      const int slot = ((ki * 4 + quad) ^ l15) * 8;
      short8v a[2], bq[4];
      #pragma unroll
      for (int t = 0; t < 2; ++t)
        a[t] = *(const short8v*)&As[(wr * 32 + t * 16 + l15) * 128 + slot];
      #pragma unroll
      for (int t = 0; t < 4; ++t)
        bq[t] = *(const short8v*)&Bs[(wc * 64 + t * 16 + l15) * 128 + slot];
      #pragma unroll
      for (int mt = 0; mt < 2; ++mt)
        #pragma unroll
        for (int nt = 0; nt < 4; ++nt)
          acc[mt][nt] = __builtin_amdgcn_mfma_f32_16x16x32_bf16(
              a[mt], bq[nt], acc[mt][nt], 0, 0, 0);
    }
    __syncthreads();
  }

  const bool as_bf16 = (g.outf == nullptr) ? true : (*g.outf != 0);
  // NT stores: gemm_dual writes only d_out (final output, never re-read).
  #pragma unroll
  for (int mt = 0; mt < 2; ++mt) {
    #pragma unroll
    for (int r = 0; r < 4; ++r) {
      int gm = bm + wr * 32 + mt * 16 + quad * 4 + r;
      if (gm >= g.M) continue;
      #pragma unroll
      for (int nt = 0; nt < 4; ++nt) {
        int gn = bn + wc * 64 + nt * 16 + l15;
        float v = acc[mt][nt][r];
        if (g.bias) v += __bfloat162float(g.bias[gn]);
        size_t o = (size_t)gm * g.N + gn;
        if (as_bf16) nt_st_bf16((bf16*)g.out + o, v);
        else         nt_st_f32((float*)g.out + o, v);
      }
    }
  }
}

// ---- counted-vmcnt K-pipelined 256x256 GEMM, BK=32, 4 slots. r7: NT
// epilogue on qkv/pos (r5 counters: attn refetches all of qkv from HBM
// regardless -- cached qkv writes only buy dirty-remote RFO cost).
__global__ __launch_bounds__(512, 2) void gemm8(
    const bf16* __restrict__ XUp, const bf16* __restrict__ Wcatp,
    const bf16* __restrict__ bcatp, bf16* __restrict__ qkvp,
    const bf16* __restrict__ posecp, const bf16* __restrict__ Wpospp,
    bf16* __restrict__ posp) {
  __shared__ bf16 smem[65536];   // 128 KiB: A[4][256*32] | B[4][256*32]
  const int tid = threadIdx.x;
  const int lane = tid & 63, wv = tid >> 6;
  const int wr = wv >> 2, wc = wv & 3;
  const int quad = lane >> 4, l15 = lane & 15;

  const bf16 *gX, *gW, *gB; bf16* gO; int gM, gN, bm, bn;
  const int bid = (int)blockIdx.x;
  if (bid < 210) {
    // bijective XCD swizzle (nwg=210: q=26,r=2), n-fastest decompose
    int xcd = bid & 7, j = bid >> 3;
    int wg = (xcd < 2 ? xcd * 27 : 54 + (xcd - 2) * 26) + j;
    bm = (wg / 6) * 256; bn = (wg % 6) * 256;
    gX = XUp; gW = Wcatp; gB = bcatp; gO = qkvp; gM = MU; gN = NU;
  } else {
    gX = posecp; gW = Wpospp; gB = nullptr; gO = posp; gM = 191; gN = 512;
    bm = 0; bn = (bid - 210) * 256;
  }

  bf16* A0 = smem;            // [4][256*32]
  bf16* B0 = smem + 32768;    // [4][256*32]

  // stage one 256x32 K-chunk (rows of 64B) into slot `dst`.
  // LDS write is linear (wave-uniform base + lane*16B); the 2-bit XOR
  // swizzle is applied on the GLOBAL k-chunk (both-sides-or-neither rule):
  // LDS[r][pos] holds global k-chunk pos ^ ((r>>1)&3)  (involution).
  auto stage = [&](const bf16* src, int rbase, int Mlim, bf16* dst, int kb) {
    #pragma unroll
    for (int j = 0; j < 2; ++j) {
      int rl = j * 128 + wv * 16 + (lane >> 2);
      int gr = rbase + rl; if (gr > Mlim - 1) gr = Mlim - 1;
      int kc = ((lane & 3) ^ ((rl >> 1) & 3)) * 8;
      const bf16* s = src + (size_t)gr * 512 + kb + kc;
      __builtin_amdgcn_global_load_lds((const AS1 void*)s,
                                       (AS3 void*)(dst + (j * 128 + wv * 16) * 32), 16, 0, 0);
    }
  };

  float4v acc[8][4] = {};
  const int pos8 = (quad ^ ((l15 >> 1) & 3)) * 8;   // read-side swizzle

  // prologue: K-steps 0,1,2 -> slots 0,1,2 (12 loads/wave)
  stage(gX, bm, gM, A0, 0);          stage(gW, bn, gN, B0, 0);
  stage(gX, bm, gM, A0 + 8192, 32);  stage(gW, bn, gN, B0 + 8192, 32);
  stage(gX, bm, gM, A0 + 16384, 64); stage(gW, bn, gN, B0 + 16384, 64);
  asm volatile("s_waitcnt vmcnt(8)" ::: "memory");   // step0 landed; 1,2 in flight
  asm volatile("s_barrier" ::: "memory");

  #pragma unroll
  for (int s = 0; s < 16; ++s) {
    if (s + 3 < 16) {
      stage(gX, bm, gM, A0 + ((s + 3) & 3) * 8192, (s + 3) * 32);
      stage(gW, bn, gN, B0 + ((s + 3) & 3) * 8192, (s + 3) * 32);
    }
    const bf16* As = A0 + (s & 3) * 8192;
    const bf16* Bs = B0 + (s & 3) * 8192;
    short8v al[8], bl[4];
    #pragma unroll
    for (int i = 0; i < 8; ++i)
      al[i] = *(const short8v*)&As[(wr * 128 + i * 16 + l15) * 32 + pos8];
    #pragma unroll
    for (int j = 0; j < 4; ++j)
      bl[j] = *(const short8v*)&Bs[(wc * 64 + j * 16 + l15) * 32 + pos8];
    asm volatile("s_barrier" ::: "memory");
    __builtin_amdgcn_s_setprio(1);
    #pragma unroll
    for (int i = 0; i < 8; ++i)
      #pragma unroll
      for (int j = 0; j < 4; ++j)
        acc[i][j] = __builtin_amdgcn_mfma_f32_16x16x32_bf16(al[i], bl[j], acc[i][j], 0, 0, 0);
    __builtin_amdgcn_s_setprio(0);
    if (s <= 12)      asm volatile("s_waitcnt vmcnt(8)" ::: "memory");
    else if (s == 13) asm volatile("s_waitcnt vmcnt(4)" ::: "memory");
    else if (s == 14) asm volatile("s_waitcnt vmcnt(0)" ::: "memory");
    if (s < 15)       asm volatile("s_barrier" ::: "memory");
  }

  // epilogue: C-layout col=lane&15, row=quad*4+reg. NT stores (r7).
  #pragma unroll
  for (int mf = 0; mf < 8; ++mf) {
    #pragma unroll
    for (int r = 0; r < 4; ++r) {
      int gm = bm + wr * 128 + mf * 16 + quad * 4 + r;
      if (gm >= gM) continue;
      #pragma unroll
      for (int nf = 0; nf < 4; ++nf) {
        int gn = bn + wc * 64 + nf * 16 + l15;
        float v = acc[mf][nf][r];
        if (gB) v += __bfloat162float(gB[gn]);
        nt_st_bf16(gO + (size_t)gm * gN + gn, v);
      }
    }
  }
}

// ---- MFMA chunk attention: one block per (c, b, h) ----
// r6 wave-local softmax version (in the 193.1us best build), kept verbatim.
// Known issue for a later round: wave 0 owns 2/5 S-row-tiles + 2x exp work
// (imbalance); barrier chain is 5.
__device__ __forceinline__ int gcol(int row, int c, int u0, int ncols) {
  if (row < c) return row;
  if (row < c + 4) return 15 + 4 * c + (row - c);
  if (row < ncols) return 79 + u0 + (row - c - 4);
  return 0;
}

__global__ __launch_bounds__(256, 2) void attn_chunk(
    const bf16* __restrict__ qkv, const bf16* __restrict__ pos,
    const bf16* __restrict__ pbu, const bf16* __restrict__ pbv,
    const int* __restrict__ lengths, bf16* __restrict__ attn,
    const int* __restrict__ flag, void* __restrict__ dout) {
  __shared__ char lds[65536];
  bf16* Vs   = (bf16*)(lds);           // [152][64]  (k>>3)-swizzled, whole life
  bf16* Aqu  = (bf16*)(lds + 19456);   // [80][64]   row&7-swizzled, whole life
  bf16* Kt   = (bf16*)(lds + 29696);   // [152][64]  row&7-swizzled, phase B
  bf16* Aqv  = (bf16*)(lds + 32768);   // [64][64]   row&7-swizzled, phase A
  bf16* Psl  = (bf16*)(lds + 40960);   // [192][64]  row&7-swizzled, phase A
  bf16* Eb   = (bf16*)(lds + 49152);   // [64][128]  bank-swizzled, phase B
  bf16* Pp   = (bf16*)(lds + 19456);   // [80][168]  softmax phase (over Aqu/Kt)
  float* rstat = (float*)(lds + 47616); // [80]  1/rowsum

  const int idx = blockIdx.x;
  const int h = idx & 7, b = (idx >> 3) & 7, c = idx >> 6;
  const int u0 = c ? (c - 1) * 64 : 0;
  const int nut = c ? 128 : 64;
  const int ncols = c + 4 + nut;
  const int q0 = c ? 63 : 127;     // pos row p = q0 - m + jl
  const int tid = threadIdx.x, lane = tid & 63, wv = tid >> 6;
  const int quad = lane >> 4, l15 = lane & 15, key = l15 & 7;
  const int lenlim = lengths[b] - u0;
  const bool obf = (*flag != 0);
  // 16-col tiles padded to full 32-col PV k-groups (PV reads Pp cols
  // [0, kmax*32); every one of those cols must be written in exp phase)
  const int ktp = ((ncols + 31) >> 5) * 2;

  // ---- stage V (152 rows, (k>>3)&7-swizzle) and PosSel (192 rows) ----
  {
    int lr = lane >> 3;
    int sbr = (lane & 7) ^ lr;
    for (int i = wv; i < 19; i += 4) {
      int row = i * 8 + lr;
      int g = gcol(row, c, u0, ncols);
      int sbv = (lane & 7) ^ (i & 7);
      const bf16* src = qkv + ((size_t)(g * 8 + b)) * NU + 1024 + h * 64 + sbv * 8;
      __builtin_amdgcn_global_load_lds((const AS1 void*)src, (AS3 void*)(Vs + i * 512), 16, 0, 0);
    }
    for (int i = wv; i < 24; i += 4) {
      int p = i * 8 + lr;
      const bf16* src = pos + (size_t)p * 512 + h * 64 + sbr * 8;
      __builtin_amdgcn_global_load_lds((const AS1 void*)src, (AS3 void*)(Psl + i * 512), 16, 0, 0);
    }
  }
  // ---- stage Aqu = q + pbu (80 rows), Aqv = q_utt + pbv (64 rows) ----
  for (int id = tid; id < 1152; id += 256) {
    bool isv = id >= 640;
    int lid = isv ? id - 640 : id;
    int m = lid >> 3, ec = lid & 7;
    int qrow;
    if (isv) qrow = 64 + 64 * c + m;
    else qrow = (m < 64) ? (64 + 64 * c + m)
              : (m < 68) ? (4 * c + (m - 64))
              : (m == 68) ? (1088 + c) : 0;
    const uint4 qa = *(const uint4*)(qkv + ((size_t)((qrow + 15) * 8 + b)) * NU + h * 64 + ec * 8);
    const uint4 ba = *(const uint4*)((isv ? pbv : pbu) + h * 64 + ec * 8);
    uint4 o;
    o.x = pk2(lo16(qa.x) + lo16(ba.x), hi16(qa.x) + hi16(ba.x));
    o.y = pk2(lo16(qa.y) + lo16(ba.y), hi16(qa.y) + hi16(ba.y));
    o.z = pk2(lo16(qa.z) + lo16(ba.z), hi16(qa.z) + hi16(ba.z));
    o.w = pk2(lo16(qa.w) + lo16(ba.w), hi16(qa.w) + hi16(ba.w));
    *(uint4*)((isv ? Aqv : Aqu) + m * 64 + (ec ^ (m & 7)) * 8) = o;
  }
  __syncthreads();  // s1

  // ---- E GEMM: wave wv owns E row-tile wv, all 12 col-tiles ----
  float4v eacc[12];
  #pragma unroll
  for (int i = 0; i < 12; ++i) eacc[i] = (float4v){0.f, 0.f, 0.f, 0.f};
  {
    short8v av[2];
    #pragma unroll
    for (int ks = 0; ks < 2; ++ks)
      av[ks] = *(const short8v*)&Aqv[(wv * 16 + l15) * 64 + ((ks * 4 + quad) ^ key) * 8];
    #pragma unroll
    for (int nti = 0; nti < 12; ++nti) {
      short8v b0 = *(const short8v*)&Psl[(nti * 16 + l15) * 64 + (quad ^ key) * 8];
      short8v b1 = *(const short8v*)&Psl[(nti * 16 + l15) * 64 + ((4 + quad) ^ key) * 8];
      eacc[nti] = __builtin_amdgcn_mfma_f32_16x16x32_bf16(av[0], b0, eacc[nti], 0, 0, 0);
      eacc[nti] = __builtin_amdgcn_mfma_f32_16x16x32_bf16(av[1], b1, eacc[nti], 0, 0, 0);
    }
  }
  __syncthreads();  // s2: Aqv/Psl dead

  // ---- stage K (row&7-swizzle) + scatter E into Eb (wave-private rows) ----
  {
    int lr = lane >> 3, sbr = (lane & 7) ^ lr;
    for (int i = wv; i < 19; i += 4) {
      int row = i * 8 + lr;
      int g = gcol(row, c, u0, ncols);
      const bf16* src = qkv + ((size_t)(g * 8 + b)) * NU + 512 + h * 64 + sbr * 8;
      __builtin_amdgcn_global_load_lds((const AS1 void*)src, (AS3 void*)(Kt + i * 512), 16, 0, 0);
    }
  }
  #pragma unroll
  for (int nti = 0; nti < 12; ++nti) {
    int p = nti * 16 + l15;
    #pragma unroll
    for (int r = 0; r < 4; ++r) {
      int m = wv * 16 + quad * 4 + r;
      int jl = p - q0 + m;
      if (jl >= 0 && jl < nut)
        Eb[m * 128 + (jl ^ (((m >> 2) & 7) << 4))] = __float2bfloat16(eacc[nti][r]);
    }
  }
  __syncthreads();  // s3: Kt landed; Eb scatter ordered before gather

  // ---- S GEMM: wave wv owns row-tiles {wv, wv+4<5}, ALL col-tiles ----
  float4v sacc[2][10];
  #pragma unroll
  for (int ti = 0; ti < 2; ++ti)
    #pragma unroll
    for (int i = 0; i < 10; ++i) sacc[ti][i] = (float4v){0.f, 0.f, 0.f, 0.f};
  {
    short8v au[2][2];
    #pragma unroll
    for (int ti = 0; ti < 2; ++ti) {
      int tt = wv + ti * 4;
      if (tt < 5) {
        #pragma unroll
        for (int ks = 0; ks < 2; ++ks)
          au[ti][ks] = *(const short8v*)&Aqu[(tt * 16 + l15) * 64 + ((ks * 4 + quad) ^ key) * 8];
      }
    }
    #pragma unroll
    for (int nti = 0; nti < 10; ++nti) {
      if (nti < ktp) {
        short8v b0 = *(const short8v*)&Kt[(nti * 16 + l15) * 64 + (quad ^ key) * 8];
        short8v b1 = *(const short8v*)&Kt[(nti * 16 + l15) * 64 + ((4 + quad) ^ key) * 8];
        #pragma unroll
        for (int ti = 0; ti < 2; ++ti) {
          int tt = wv + ti * 4;
          if (tt < 5) {
            sacc[ti][nti] = __builtin_amdgcn_mfma_f32_16x16x32_bf16(au[ti][0], b0, sacc[ti][nti], 0, 0, 0);
            sacc[ti][nti] = __builtin_amdgcn_mfma_f32_16x16x32_bf16(au[ti][1], b1, sacc[ti][nti], 0, 0, 0);
          }
        }
      }
    }
  }

  // ---- assembly: + E gather (wave-private), masks, scale ----
  #pragma unroll
  for (int nti = 0; nti < 10; ++nti) {
    if (nti < ktp) {
      int colv = nti * 16 + l15;
      int jl = colv - (c + 4);
      bool cvalid = (colv < ncols) && !(jl >= 0 && jl >= lenlim);
      #pragma unroll
      for (int ti = 0; ti < 2; ++ti) {
        int tt = wv + ti * 4;
        if (tt < 5) {
          #pragma unroll
          for (int r = 0; r < 4; ++r) {
            float s = sacc[ti][nti][r];
            if (cvalid) {
              if (tt < 4 && jl >= 0) {
                int m = tt * 16 + quad * 4 + r;
                s += __bfloat162float(Eb[m * 128 + (jl ^ (((m >> 2) & 7) << 4))]);
              }
              s *= 0.125f;
            } else s = -1e30f;
            sacc[ti][nti][r] = s;
          }
        }
      }
    }
  }

  // ---- softmax max: wave-local (row cols live on 16 l15-lanes) ----
  float rmx[2][4], rsum[2][4];
  #pragma unroll
  for (int ti = 0; ti < 2; ++ti) {
    int tt = wv + ti * 4;
    if (tt < 5) {
      #pragma unroll
      for (int r = 0; r < 4; ++r) {
        float v = -3e38f;
        #pragma unroll
        for (int nti = 0; nti < 10; ++nti)
          if (nti < ktp) v = fmaxf(v, sacc[ti][nti][r]);
        v = fmaxf(v, __shfl_xor(v, 1));
        v = fmaxf(v, __shfl_xor(v, 2));
        v = fmaxf(v, __shfl_xor(v, 4));
        v = fmaxf(v, __shfl_xor(v, 8));
        rmx[ti][r] = v;
        rsum[ti][r] = 0.f;
      }
    }
  }
  __syncthreads();  // s4: Aqu/Kt dead (S GEMM + assembly complete block-wide)

  // ---- exp, write P (wave-private rows), row sums, rstat ----
  #pragma unroll
  for (int nti = 0; nti < 10; ++nti) {
    if (nti < ktp) {
      int colv = nti * 16 + l15;
      #pragma unroll
      for (int ti = 0; ti < 2; ++ti) {
        int tt = wv + ti * 4;
        if (tt < 5) {
          #pragma unroll
          for (int r = 0; r < 4; ++r) {
            float p = __expf(sacc[ti][nti][r] - rmx[ti][r]);
            Pp[(tt * 16 + quad * 4 + r) * 168 + colv] = __float2bfloat16(p);
            rsum[ti][r] += p;
          }
        }
      }
    }
  }
  #pragma unroll
  for (int ti = 0; ti < 2; ++ti) {
    int tt = wv + ti * 4;
    if (tt < 5) {
      #pragma unroll
      for (int r = 0; r < 4; ++r) {
        float v = rsum[ti][r];
        v += __shfl_xor(v, 1);
        v += __shfl_xor(v, 2);
        v += __shfl_xor(v, 4);
        v += __shfl_xor(v, 8);
        if (l15 == 0) rstat[tt * 16 + quad * 4 + r] = 1.f / v;
      }
    }
  }
  __syncthreads();  // s5: Pp + rstat visible to all waves

  // ---- PV GEMM: O[80 x 64] = P @ V ----
  const int kmax = (ncols + 31) >> 5;
  float4v oacc[5];
  #pragma unroll
  for (int mt = 0; mt < 5; ++mt) oacc[mt] = (float4v){0.f, 0.f, 0.f, 0.f};
  const int ehi = (wv * 16 + l15) >> 3, elo = l15 & 7;
  for (int ks = 0; ks < kmax; ++ks) {
    short8v bq;
    const int blk = ehi ^ ((ks * 4 + quad) & 7);
    #pragma unroll
    for (int j = 0; j < 8; ++j)
      bq[j] = ((const short*)Vs)[(ks * 32 + quad * 8 + j) * 64 + blk * 8 + elo];
    #pragma unroll
    for (int mt = 0; mt < 5; ++mt) {
      short8v af = *(const short8v*)&Pp[(mt * 16 + l15) * 168 + ks * 32 + quad * 8];
      oacc[mt] = __builtin_amdgcn_mfma_f32_16x16x32_bf16(af, bq, oacc[mt], 0, 0, 0);
    }
  }

  // ---- epilogue: rows m<68 -> attn (cached, outproj re-reads);
  //      m==68 (summary) -> d_out (NT, write-only) ----
  #pragma unroll
  for (int mt = 0; mt < 5; ++mt) {
    #pragma unroll
    for (int r = 0; r < 4; ++r) {
      int m = mt * 16 + quad * 4 + r;
      if (m >= 69) continue;
      float o = oacc[mt][r] * rstat[m];
      if (m < 68) {
        int qrow = (m < 64) ? (64 + 64 * c + m) : (4 * c + (m - 64));
        attn[((size_t)(qrow * 8 + b)) * 512 + h * 64 + wv * 16 + l15] = __float2bfloat16(o);
      } else {
        float v = fminf(fmaxf(o, -10.f), 10.f);
        size_t oi = (size_t)1088 * 8 * 512 + ((size_t)(c * 8 + b)) * 512 + h * 64 + wv * 16 + l15;
        if (obf) nt_st_bf16((bf16*)dout + oi, v);
        else     nt_st_f32((float*)dout + oi, v);
      }
    }
  }
}

static inline int cdiv(int a, int b) { return (a + b - 1) / b; }

extern "C" void kernel_launch(void* const* d_in, const int* in_sizes, int n_in,
                              void* d_out, int out_size, void* d_ws, size_t ws_size,
                              hipStream_t stream) {
  const void* utter = d_in[0];
  const int*  lens  = (const int*)d_in[1];
  const void* rctx  = d_in[2];
  const void* summ  = d_in[3];
  const void* memry = d_in[4];
  // d_in[5] attention_mask: analytic, never read
  const void* pose  = d_in[6];
  const void* W_kv  = d_in[7];
  const void* b_kv  = d_in[8];
  const void* W_q   = d_in[9];
  const void* b_q   = d_in[10];
  const void* W_out = d_in[11];
  const void* b_out = d_in[12];
  const void* W_pos = d_in[13];
  const void* pbu   = d_in[14];
  const void* pbv   = d_in[15];

  const unsigned SZ_MM = MM * BB * DD;   // 61440
  const unsigned SZ_RC = RR * BB * DD;   // 262144
  const unsigned SZ_UT = UU * BB * DD;   // 4194304
  const unsigned SZ_SM = SS * BB * DD;   // 65536
  const unsigned N_XU  = SZ_MM + SZ_RC + SZ_UT + SZ_SM;  // 4583424
  const unsigned SZ_PS = 191 * DD;       // 97792

  int*  flag = (int*)d_ws;
  bf16* base = (bf16*)((char*)d_ws + 64);
  unsigned off = 0;
  bf16* XU    = base + off; unsigned o_XU    = off; off += N_XU;
  bf16* posec = base + off; unsigned o_posec = off; off += 192 * DD;
  bf16* Wcat  = base + off; unsigned o_Wcat  = off; off += (unsigned)NU * DD;
  bf16* bcat  = base + off; unsigned o_bcat  = off; off += NU;
  bf16* Woutp = base + off; unsigned o_Wout  = off; off += DD * DD;
  bf16* boutp = base + off; unsigned o_bout  = off; off += DD;
  bf16* Wposp = base + off; unsigned o_Wpos  = off; off += DD * DD;
  bf16* pbuc  = base + off; unsigned o_pbu   = off; off += DD;
  bf16* pbvc  = base + off; unsigned o_pbv   = off; off += DD;
  bf16* qkv   = base + off; off += (unsigned)(MU + 8) * NU;
  bf16* pos   = base + off; off += 192 * DD;
  bf16* attn  = base + off; off += QQ * BB * DD;

  // Fused pack: 14 segments (union X = [mem | rc | utt | summ])
  PackDesc pd;
  const void* srcs[14]  = {memry, rctx, utter, summ, pose,
                           W_q, W_kv, b_q, b_kv, W_out, b_out, W_pos, pbu, pbv};
  unsigned    soffs[14] = {0, 0, 0, 0, 896u * DD, 0, 0, 0, 0, 0, 0, 0, 0, 0};
  unsigned    doffs[14] = {o_XU, o_XU + SZ_MM, o_XU + SZ_MM + SZ_RC,
                           o_XU + SZ_MM + SZ_RC + SZ_UT, o_posec,
                           o_Wcat, o_Wcat + DD * DD, o_bcat, o_bcat + DD,
                           o_Wout, o_bout, o_Wpos, o_pbu, o_pbv};
  unsigned    ns[14]    = {SZ_MM, SZ_RC, SZ_UT, SZ_SM, SZ_PS,
                           DD * DD, 2 * DD * DD, DD, 2 * DD,
                           DD * DD, DD, DD * DD, DD, DD};
  unsigned cum = 0;
  for (int i = 0; i < 14; ++i) {
    pd.src[i] = srcs[i]; pd.srcoff[i] = soffs[i]; pd.dstoff[i] = doffs[i];
    pd.cum[i] = cum; cum += ns[i] / 8;
  }
  pd.src[14] = pbv; pd.srcoff[14] = 0; pd.dstoff[14] = o_pbv;
  pd.src[15] = pbv; pd.srcoff[15] = 0; pd.dstoff[15] = o_pbv;
  pd.cum[14] = cum; pd.cum[15] = cum; pd.cum[16] = cum;
  int nchunks = (int)cum;
  pack_all<<<dim3(cdiv(nchunks, 256)), dim3(256), 0, stream>>>(pd, base, utter, flag, nchunks);

  // fused QKV GEMM (8952 x 1536 x 512) + pos GEMM (191 x 512 x 512):
  // counted-vmcnt K-pipeline, 210 QKV blocks + 2 pos blocks, 512 threads.
  gemm8<<<dim3(212), dim3(512), 0, stream>>>(XU, Wcat, bcat, qkv, posec, Wposp, pos);

  // attention: one block per (c, b, h); writes attn rows + clipped summary rows
  attn_chunk<<<dim3(1024), dim3(256), 0, stream>>>(qkv, pos, pbuc, pbvc, lens, attn,
                                                   flag, d_out);

  // out_ru = attn[:1088] @ W_out^T + b_out (136 m-tiles * 4 n = 544 blocks)
  GemmP go{attn, Woutp, boutp, d_out, (RR + UU) * BB, DD, DD, flag};
  gemm_dual<<<dim3(4, 136), dim3(256), 0, stream>>>(go, go, 136);
}

// Round 10
// 189.507 us; speedup vs baseline: 1.0230x; 1.0230x over previous
//
#include <hip/hip_runtime.h>
#include <hip/hip_bf16.h>

typedef __hip_bfloat16 bf16;
typedef __attribute__((ext_vector_type(8))) short short8v;   // 8 bf16 (4 VGPRs)
typedef __attribute__((ext_vector_type(4))) float float4v;   // MFMA C/D frag
typedef __attribute__((ext_vector_type(4))) unsigned int uint4v; // NT-store safe

// Problem constants
#define UU 1024
#define BB 8
#define DD 512
#define HH 8
#define HD 64
#define RR 64
#define SS 16
#define MM 15
#define QQ 1104   // R + U + S
#define KVL 1103  // M + R + U
#define PEL 2047
#define NU 1536   // fused QKV output width
#define MU 8952   // union rows (15+64+1024+16)*8

#define AS1 __attribute__((address_space(1)))
#define AS3 __attribute__((address_space(3)))

__device__ __forceinline__ float lo16(unsigned u) { return __uint_as_float(u << 16); }
__device__ __forceinline__ float hi16(unsigned u) { return __uint_as_float(u & 0xffff0000u); }
__device__ __forceinline__ unsigned pk2(float a, float b) {
  unsigned short x = __builtin_bit_cast(unsigned short, __float2bfloat16(a));
  unsigned short y = __builtin_bit_cast(unsigned short, __float2bfloat16(b));
  return (unsigned)x | ((unsigned)y << 16);
}

// r8 SYNTHESIS: gemm8 / attn / old QKV-gemm all plateau at ~40-44us and
// ~0.9 TB/s regardless of schedule; the fill hits 6.3 TB/s. Common factor:
// OUR stores are partial-line (2B/lane scalar bf16, quad-scattered 32B
// chunks) -> RFO on poisoned lines; the fill writes full lines. r9 bounces
// epilogues through LDS to emit full-line 16B/lane stores.
// r3 LESSON: NT only where nothing re-reads (d_out, qkv, XU). attn-rows
// stay cached (outproj reads them).
// r4 LESSON: 47.9KB V-late LDS overlay NaN'd twice; attn keeps 64KB layout.
// r7 LESSON: __builtin_nontemporal_store rejects HIP's uint4 class type --
// bit_cast to clang ext_vector (uint4v) first.
__device__ __forceinline__ void nt_st_bf16(bf16* p, float v) {
  bf16 t = __float2bfloat16(v);
  __builtin_nontemporal_store(__builtin_bit_cast(short, t), (short*)p);
}
__device__ __forceinline__ void nt_st_f32(float* p, float v) {
  __builtin_nontemporal_store(v, p);
}
__device__ __forceinline__ void nt_st_u4(void* p, uint4 v) {
  __builtin_nontemporal_store(__builtin_bit_cast(uint4v, v), (uint4v*)p);
}

// ---- fused canonicalization + in-block dtype detection ----
// Copies into workspace (even for bf16): fp32->bf16 narrowing halves the
// GEMM's read traffic. XU/posec segments (s<5) NT (streamed, read-once);
// weights (s>=5, small+hot) cached. Stores are 16B/lane = full-line.
struct PackDesc {
  const void* src[16];
  unsigned int srcoff[16];
  unsigned int dstoff[16];
  unsigned int cum[17];   // cumulative 8-element chunks
};

__global__ __launch_bounds__(256) void pack_all(PackDesc d, bf16* base,
                                                const void* __restrict__ probe,
                                                int* __restrict__ flagout,
                                                int nchunks) {
  __shared__ int wsum[4];
  const unsigned short* p = (const unsigned short*)probe;
  int big = 0;
  for (int i = threadIdx.x; i < 4096; i += 256)
    big += (((p[i] >> 7) & 0xFF) >= 137) ? 1 : 0;
  #pragma unroll
  for (int off = 32; off; off >>= 1) big += __shfl_down(big, off);
  if ((threadIdx.x & 63) == 0) wsum[threadIdx.x >> 6] = big;
  __syncthreads();
  const int flag = (wsum[0] + wsum[1] + wsum[2] + wsum[3] < 16) ? 1 : 0;
  if (threadIdx.x == 0 && blockIdx.x == 0) *flagout = flag;

  int g = blockIdx.x * 256 + threadIdx.x;
  if (g >= nchunks) return;
  int s = 0;
  #pragma unroll
  for (int i = 1; i < 17; ++i) s += (g >= d.cum[i]) ? 1 : 0;
  unsigned local = (g - d.cum[s]) * 8u;
  bf16* dst = base + d.dstoff[s] + local;
  uint4 o;
  if (flag) {
    o = *(const uint4*)((const bf16*)d.src[s] + d.srcoff[s] + local);
  } else {
    const float* fp = (const float*)d.src[s] + d.srcoff[s] + local;
    o.x = pk2(fp[0], fp[1]);
    o.y = pk2(fp[2], fp[3]);
    o.z = pk2(fp[4], fp[5]);
    o.w = pk2(fp[6], fp[7]);
  }
  if (s < 5) nt_st_u4(dst, o);     // XU union + posec: streamed, read-once
  else       *(uint4*)dst = o;     // weights/biases: small, keep cached
}

// ---- MFMA GEMM, 64x128 tile, BK=128, XOR-swizzled LDS, 48KB -> 3 blocks/CU.
// Out-projection only (writes d_out) -> NT epilogue. For this dataset the
// output is fp32 (64B full lines per quad-chunk) -> no RFO issue; keep the
// direct store path.
struct GemmP {
  const bf16* X; const bf16* W; const bf16* bias; void* out;
  int M, N, K; const int* outf;
};

__global__ __launch_bounds__(256, 3) void gemm_dual(GemmP g0, GemmP g1, int ysplit) {
  __shared__ bf16 As[64 * 128];
  __shared__ bf16 Bs[128 * 128];
  GemmP g; int bm, bn;
  if ((int)blockIdx.y < ysplit) {
    g = g0;
    int bi = (int)blockIdx.y * (int)gridDim.x + (int)blockIdx.x;
    int nbn = g0.N >> 7;
    int j = bi >> 3;
    int bmi = (bi & 7) + (j / nbn) * 8;
    int bni = j % nbn;
    if (bmi >= ((g0.M + 63) >> 6)) return;
    bm = bmi * 64; bn = bni * 128;
  } else {
    g = g1;
    int nt = g1.N >> 7;
    int bi = ((int)blockIdx.y - ysplit) * gridDim.x + blockIdx.x;
    if (bi >= ((g1.M + 63) >> 6) * nt) return;
    bm = (bi / nt) * 64; bn = (bi % nt) * 128;
  }
  const int tid = threadIdx.x;
  const int lane = tid & 63, wv = tid >> 6;
  const int wr = wv >> 1, wc = wv & 1;
  const int l4 = lane >> 4;            // row within 4-row staging group
  const int lb = lane & 15;            // 16B block within 256B row
  const int quad = lane >> 4, l15 = lane & 15;

  float4v acc[2][4] = {};

  for (int kb = 0; kb < g.K; kb += 128) {
    // stage A: 64 rows x 128 cols (16 KB)
    #pragma unroll
    for (int i = 0; i < 4; ++i) {
      int r = wv * 16 + i * 4 + l4;
      int gm = bm + r; if (gm > g.M - 1) gm = g.M - 1;
      const bf16* src = g.X + (size_t)gm * g.K + kb + ((lb ^ (r & 15)) * 8);
      __builtin_amdgcn_global_load_lds((const AS1 void*)src,
                                       (AS3 void*)&As[(wv * 16 + i * 4) * 128], 16, 0, 0);
    }
    // stage B: 128 rows x 128 cols (32 KB)
    #pragma unroll
    for (int i = 0; i < 8; ++i) {
      int r = wv * 32 + i * 4 + l4;
      int gn = bn + r; if (gn > g.N - 1) gn = g.N - 1;
      const bf16* src = g.W + (size_t)gn * g.K + kb + ((lb ^ (r & 15)) * 8);
      __builtin_amdgcn_global_load_lds((const AS1 void*)src,
                                       (AS3 void*)&Bs[(wv * 32 + i * 4) * 128], 16, 0, 0);
    }
    __syncthreads();
    #pragma unroll
    for (int ki = 0; ki < 4; ++ki) {
      const int slot = ((ki * 4 + quad) ^ l15) * 8;
      short8v a[2], bq[4];
      #pragma unroll
      for (int t = 0; t < 2; ++t)
        a[t] = *(const short8v*)&As[(wr * 32 + t * 16 + l15) * 128 + slot];
      #pragma unroll
      for (int t = 0; t < 4; ++t)
        bq[t] = *(const short8v*)&Bs[(wc * 64 + t * 16 + l15) * 128 + slot];
      #pragma unroll
      for (int mt = 0; mt < 2; ++mt)
        #pragma unroll
        for (int nt = 0; nt < 4; ++nt)
          acc[mt][nt] = __builtin_amdgcn_mfma_f32_16x16x32_bf16(
              a[mt], bq[nt], acc[mt][nt], 0, 0, 0);
    }
    __syncthreads();
  }

  const bool as_bf16 = (g.outf == nullptr) ? true : (*g.outf != 0);
  // NT stores: gemm_dual writes only d_out (final output, never re-read).
  #pragma unroll
  for (int mt = 0; mt < 2; ++mt) {
    #pragma unroll
    for (int r = 0; r < 4; ++r) {
      int gm = bm + wr * 32 + mt * 16 + quad * 4 + r;
      if (gm >= g.M) continue;
      #pragma unroll
      for (int nt = 0; nt < 4; ++nt) {
        int gn = bn + wc * 64 + nt * 16 + l15;
        float v = acc[mt][nt][r];
        if (g.bias) v += __bfloat162float(g.bias[gn]);
        size_t o = (size_t)gm * g.N + gn;
        if (as_bf16) nt_st_bf16((bf16*)g.out + o, v);
        else         nt_st_f32((float*)g.out + o, v);
      }
    }
  }
}

// ---- counted-vmcnt K-pipelined 256x256 GEMM, BK=32, 4 slots. r9: epilogue
// bounces C through the (dead) 128KB smem so global writes are full-line
// 16B/lane NT streams instead of quad-scattered 32B bf16 partials (RFO).
__global__ __launch_bounds__(512, 2) void gemm8(
    const bf16* __restrict__ XUp, const bf16* __restrict__ Wcatp,
    const bf16* __restrict__ bcatp, bf16* __restrict__ qkvp,
    const bf16* __restrict__ posecp, const bf16* __restrict__ Wpospp,
    bf16* __restrict__ posp) {
  __shared__ bf16 smem[65536];   // 128 KiB: A[4][256*32] | B[4][256*32]
  const int tid = threadIdx.x;
  const int lane = tid & 63, wv = tid >> 6;
  const int wr = wv >> 2, wc = wv & 3;
  const int quad = lane >> 4, l15 = lane & 15;

  const bf16 *gX, *gW, *gB; bf16* gO; int gM, gN, bm, bn;
  const int bid = (int)blockIdx.x;
  if (bid < 210) {
    // bijective XCD swizzle (nwg=210: q=26,r=2), n-fastest decompose
    int xcd = bid & 7, j = bid >> 3;
    int wg = (xcd < 2 ? xcd * 27 : 54 + (xcd - 2) * 26) + j;
    bm = (wg / 6) * 256; bn = (wg % 6) * 256;
    gX = XUp; gW = Wcatp; gB = bcatp; gO = qkvp; gM = MU; gN = NU;
  } else {
    gX = posecp; gW = Wpospp; gB = nullptr; gO = posp; gM = 191; gN = 512;
    bm = 0; bn = (bid - 210) * 256;
  }

  bf16* A0 = smem;            // [4][256*32]
  bf16* B0 = smem + 32768;    // [4][256*32]

  // stage one 256x32 K-chunk (rows of 64B) into slot `dst`.
  // LDS write is linear (wave-uniform base + lane*16B); the 2-bit XOR
  // swizzle is applied on the GLOBAL k-chunk (both-sides-or-neither rule):
  // LDS[r][pos] holds global k-chunk pos ^ ((r>>1)&3)  (involution).
  auto stage = [&](const bf16* src, int rbase, int Mlim, bf16* dst, int kb) {
    #pragma unroll
    for (int j = 0; j < 2; ++j) {
      int rl = j * 128 + wv * 16 + (lane >> 2);
      int gr = rbase + rl; if (gr > Mlim - 1) gr = Mlim - 1;
      int kc = ((lane & 3) ^ ((rl >> 1) & 3)) * 8;
      const bf16* s = src + (size_t)gr * 512 + kb + kc;
      __builtin_amdgcn_global_load_lds((const AS1 void*)s,
                                       (AS3 void*)(dst + (j * 128 + wv * 16) * 32), 16, 0, 0);
    }
  };

  float4v acc[8][4] = {};
  const int pos8 = (quad ^ ((l15 >> 1) & 3)) * 8;   // read-side swizzle

  // prologue: K-steps 0,1,2 -> slots 0,1,2 (12 loads/wave)
  stage(gX, bm, gM, A0, 0);          stage(gW, bn, gN, B0, 0);
  stage(gX, bm, gM, A0 + 8192, 32);  stage(gW, bn, gN, B0 + 8192, 32);
  stage(gX, bm, gM, A0 + 16384, 64); stage(gW, bn, gN, B0 + 16384, 64);
  asm volatile("s_waitcnt vmcnt(8)" ::: "memory");   // step0 landed; 1,2 in flight
  asm volatile("s_barrier" ::: "memory");

  #pragma unroll
  for (int s = 0; s < 16; ++s) {
    if (s + 3 < 16) {
      stage(gX, bm, gM, A0 + ((s + 3) & 3) * 8192, (s + 3) * 32);
      stage(gW, bn, gN, B0 + ((s + 3) & 3) * 8192, (s + 3) * 32);
    }
    const bf16* As = A0 + (s & 3) * 8192;
    const bf16* Bs = B0 + (s & 3) * 8192;
    short8v al[8], bl[4];
    #pragma unroll
    for (int i = 0; i < 8; ++i)
      al[i] = *(const short8v*)&As[(wr * 128 + i * 16 + l15) * 32 + pos8];
    #pragma unroll
    for (int j = 0; j < 4; ++j)
      bl[j] = *(const short8v*)&Bs[(wc * 64 + j * 16 + l15) * 32 + pos8];
    asm volatile("s_barrier" ::: "memory");
    __builtin_amdgcn_s_setprio(1);
    #pragma unroll
    for (int i = 0; i < 8; ++i)
      #pragma unroll
      for (int j = 0; j < 4; ++j)
        acc[i][j] = __builtin_amdgcn_mfma_f32_16x16x32_bf16(al[i], bl[j], acc[i][j], 0, 0, 0);
    __builtin_amdgcn_s_setprio(0);
    if (s <= 12)      asm volatile("s_waitcnt vmcnt(8)" ::: "memory");
    else if (s == 13) asm volatile("s_waitcnt vmcnt(4)" ::: "memory");
    else if (s == 14) asm volatile("s_waitcnt vmcnt(0)" ::: "memory");
    if (s < 15)       asm volatile("s_barrier" ::: "memory");
  }

  // ---- C epilogue via LDS bounce (r9): smem dead after the K-loop ----
  __syncthreads();   // all waves done reading slot 3
  {
    bf16* Cs = smem;   // [256][256] row-major C tile, 128 KiB
    #pragma unroll
    for (int mf = 0; mf < 8; ++mf) {
      #pragma unroll
      for (int r = 0; r < 4; ++r) {
        int row = wr * 128 + mf * 16 + quad * 4 + r;
        #pragma unroll
        for (int nf = 0; nf < 4; ++nf) {
          int col = wc * 64 + nf * 16 + l15;
          float v = acc[mf][nf][r];
          if (gB) v += __bfloat162float(gB[bn + col]);
          Cs[row * 256 + col] = __float2bfloat16(v);
        }
      }
    }
    __syncthreads();
    // readout: each instruction streams 512B-contiguous full lines per row
    #pragma unroll
    for (int it = 0; it < 16; ++it) {
      int ci = tid + it * 512;
      int row = ci >> 5, ch = ci & 31;
      int gm = bm + row;
      if (gm < gM) {
        uint4 v = *(const uint4*)&Cs[row * 256 + ch * 8];
        nt_st_u4(gO + (size_t)gm * gN + bn + ch * 8, v);
      }
    }
  }
}

// ---- MFMA chunk attention: one block per (c, b, h) ----
// r6 wave-local softmax structure. r9: output epilogue bounces O[80][64]
// through the dead Eb region (disjoint from Vs/Pp that PV reads -> no
// overlay hazard; r4's NaN overlay is NOT re-attempted) so attn-row writes
// are 16B/lane full-line cached stores instead of 32B quad-partials.
__device__ __forceinline__ int gcol(int row, int c, int u0, int ncols) {
  if (row < c) return row;
  if (row < c + 4) return 15 + 4 * c + (row - c);
  if (row < ncols) return 79 + u0 + (row - c - 4);
  return 0;
}

__global__ __launch_bounds__(256, 2) void attn_chunk(
    const bf16* __restrict__ qkv, const bf16* __restrict__ pos,
    const bf16* __restrict__ pbu, const bf16* __restrict__ pbv,
    const int* __restrict__ lengths, bf16* __restrict__ attn,
    const int* __restrict__ flag, void* __restrict__ dout) {
  __shared__ char lds[65536];
  bf16* Vs   = (bf16*)(lds);           // [152][64]  (k>>3)-swizzled, whole life
  bf16* Aqu  = (bf16*)(lds + 19456);   // [80][64]   row&7-swizzled, whole life
  bf16* Kt   = (bf16*)(lds + 29696);   // [152][64]  row&7-swizzled, phase B
  bf16* Aqv  = (bf16*)(lds + 32768);   // [64][64]   row&7-swizzled, phase A
  bf16* Psl  = (bf16*)(lds + 40960);   // [192][64]  row&7-swizzled, phase A
  bf16* Eb   = (bf16*)(lds + 49152);   // [64][128]  bank-swizzled, phase B
  bf16* Pp   = (bf16*)(lds + 19456);   // [80][168]  softmax phase (over Aqu/Kt)
  bf16* Ol   = (bf16*)(lds + 49152);   // [80][64]   epilogue (over dead Eb)
  float* rstat = (float*)(lds + 47616); // [80]  1/rowsum

  const int idx = blockIdx.x;
  const int h = idx & 7, b = (idx >> 3) & 7, c = idx >> 6;
  const int u0 = c ? (c - 1) * 64 : 0;
  const int nut = c ? 128 : 64;
  const int ncols = c + 4 + nut;
  const int q0 = c ? 63 : 127;     // pos row p = q0 - m + jl
  const int tid = threadIdx.x, lane = tid & 63, wv = tid >> 6;
  const int quad = lane >> 4, l15 = lane & 15, key = l15 & 7;
  const int lenlim = lengths[b] - u0;
  const bool obf = (*flag != 0);
  // 16-col tiles padded to full 32-col PV k-groups (PV reads Pp cols
  // [0, kmax*32); every one of those cols must be written in exp phase)
  const int ktp = ((ncols + 31) >> 5) * 2;

  // ---- stage V (152 rows, (k>>3)&7-swizzle) and PosSel (192 rows) ----
  {
    int lr = lane >> 3;
    int sbr = (lane & 7) ^ lr;
    for (int i = wv; i < 19; i += 4) {
      int row = i * 8 + lr;
      int g = gcol(row, c, u0, ncols);
      int sbv = (lane & 7) ^ (i & 7);
      const bf16* src = qkv + ((size_t)(g * 8 + b)) * NU + 1024 + h * 64 + sbv * 8;
      __builtin_amdgcn_global_load_lds((const AS1 void*)src, (AS3 void*)(Vs + i * 512), 16, 0, 0);
    }
    for (int i = wv; i < 24; i += 4) {
      int p = i * 8 + lr;
      const bf16* src = pos + (size_t)p * 512 + h * 64 + sbr * 8;
      __builtin_amdgcn_global_load_lds((const AS1 void*)src, (AS3 void*)(Psl + i * 512), 16, 0, 0);
    }
  }
  // ---- stage Aqu = q + pbu (80 rows), Aqv = q_utt + pbv (64 rows) ----
  for (int id = tid; id < 1152; id += 256) {
    bool isv = id >= 640;
    int lid = isv ? id - 640 : id;
    int m = lid >> 3, ec = lid & 7;
    int qrow;
    if (isv) qrow = 64 + 64 * c + m;
    else qrow = (m < 64) ? (64 + 64 * c + m)
              : (m < 68) ? (4 * c + (m - 64))
              : (m == 68) ? (1088 + c) : 0;
    const uint4 qa = *(const uint4*)(qkv + ((size_t)((qrow + 15) * 8 + b)) * NU + h * 64 + ec * 8);
    const uint4 ba = *(const uint4*)((isv ? pbv : pbu) + h * 64 + ec * 8);
    uint4 o;
    o.x = pk2(lo16(qa.x) + lo16(ba.x), hi16(qa.x) + hi16(ba.x));
    o.y = pk2(lo16(qa.y) + lo16(ba.y), hi16(qa.y) + hi16(ba.y));
    o.z = pk2(lo16(qa.z) + lo16(ba.z), hi16(qa.z) + hi16(ba.z));
    o.w = pk2(lo16(qa.w) + lo16(ba.w), hi16(qa.w) + hi16(ba.w));
    *(uint4*)((isv ? Aqv : Aqu) + m * 64 + (ec ^ (m & 7)) * 8) = o;
  }
  __syncthreads();  // s1

  // ---- E GEMM: wave wv owns E row-tile wv, all 12 col-tiles ----
  float4v eacc[12];
  #pragma unroll
  for (int i = 0; i < 12; ++i) eacc[i] = (float4v){0.f, 0.f, 0.f, 0.f};
  {
    short8v av[2];
    #pragma unroll
    for (int ks = 0; ks < 2; ++ks)
      av[ks] = *(const short8v*)&Aqv[(wv * 16 + l15) * 64 + ((ks * 4 + quad) ^ key) * 8];
    #pragma unroll
    for (int nti = 0; nti < 12; ++nti) {
      short8v b0 = *(const short8v*)&Psl[(nti * 16 + l15) * 64 + (quad ^ key) * 8];
      short8v b1 = *(const short8v*)&Psl[(nti * 16 + l15) * 64 + ((4 + quad) ^ key) * 8];
      eacc[nti] = __builtin_amdgcn_mfma_f32_16x16x32_bf16(av[0], b0, eacc[nti], 0, 0, 0);
      eacc[nti] = __builtin_amdgcn_mfma_f32_16x16x32_bf16(av[1], b1, eacc[nti], 0, 0, 0);
    }
  }
  __syncthreads();  // s2: Aqv/Psl dead

  // ---- stage K (row&7-swizzle) + scatter E into Eb (wave-private rows) ----
  {
    int lr = lane >> 3, sbr = (lane & 7) ^ lr;
    for (int i = wv; i < 19; i += 4) {
      int row = i * 8 + lr;
      int g = gcol(row, c, u0, ncols);
      const bf16* src = qkv + ((size_t)(g * 8 + b)) * NU + 512 + h * 64 + sbr * 8;
      __builtin_amdgcn_global_load_lds((const AS1 void*)src, (AS3 void*)(Kt + i * 512), 16, 0, 0);
    }
  }
  #pragma unroll
  for (int nti = 0; nti < 12; ++nti) {
    int p = nti * 16 + l15;
    #pragma unroll
    for (int r = 0; r < 4; ++r) {
      int m = wv * 16 + quad * 4 + r;
      int jl = p - q0 + m;
      if (jl >= 0 && jl < nut)
        Eb[m * 128 + (jl ^ (((m >> 2) & 7) << 4))] = __float2bfloat16(eacc[nti][r]);
    }
  }
  __syncthreads();  // s3: Kt landed; Eb scatter ordered before gather

  // ---- S GEMM: wave wv owns row-tiles {wv, wv+4<5}, ALL col-tiles ----
  float4v sacc[2][10];
  #pragma unroll
  for (int ti = 0; ti < 2; ++ti)
    #pragma unroll
    for (int i = 0; i < 10; ++i) sacc[ti][i] = (float4v){0.f, 0.f, 0.f, 0.f};
  {
    short8v au[2][2];
    #pragma unroll
    for (int ti = 0; ti < 2; ++ti) {
      int tt = wv + ti * 4;
      if (tt < 5) {
        #pragma unroll
        for (int ks = 0; ks < 2; ++ks)
          au[ti][ks] = *(const short8v*)&Aqu[(tt * 16 + l15) * 64 + ((ks * 4 + quad) ^ key) * 8];
      }
    }
    #pragma unroll
    for (int nti = 0; nti < 10; ++nti) {
      if (nti < ktp) {
        short8v b0 = *(const short8v*)&Kt[(nti * 16 + l15) * 64 + (quad ^ key) * 8];
        short8v b1 = *(const short8v*)&Kt[(nti * 16 + l15) * 64 + ((4 + quad) ^ key) * 8];
        #pragma unroll
        for (int ti = 0; ti < 2; ++ti) {
          int tt = wv + ti * 4;
          if (tt < 5) {
            sacc[ti][nti] = __builtin_amdgcn_mfma_f32_16x16x32_bf16(au[ti][0], b0, sacc[ti][nti], 0, 0, 0);
            sacc[ti][nti] = __builtin_amdgcn_mfma_f32_16x16x32_bf16(au[ti][1], b1, sacc[ti][nti], 0, 0, 0);
          }
        }
      }
    }
  }

  // ---- assembly: + E gather (wave-private), masks, scale ----
  #pragma unroll
  for (int nti = 0; nti < 10; ++nti) {
    if (nti < ktp) {
      int colv = nti * 16 + l15;
      int jl = colv - (c + 4);
      bool cvalid = (colv < ncols) && !(jl >= 0 && jl >= lenlim);
      #pragma unroll
      for (int ti = 0; ti < 2; ++ti) {
        int tt = wv + ti * 4;
        if (tt < 5) {
          #pragma unroll
          for (int r = 0; r < 4; ++r) {
            float s = sacc[ti][nti][r];
            if (cvalid) {
              if (tt < 4 && jl >= 0) {
                int m = tt * 16 + quad * 4 + r;
                s += __bfloat162float(Eb[m * 128 + (jl ^ (((m >> 2) & 7) << 4))]);
              }
              s *= 0.125f;
            } else s = -1e30f;
            sacc[ti][nti][r] = s;
          }
        }
      }
    }
  }

  // ---- softmax max: wave-local (row cols live on 16 l15-lanes) ----
  float rmx[2][4], rsum[2][4];
  #pragma unroll
  for (int ti = 0; ti < 2; ++ti) {
    int tt = wv + ti * 4;
    if (tt < 5) {
      #pragma unroll
      for (int r = 0; r < 4; ++r) {
        float v = -3e38f;
        #pragma unroll
        for (int nti = 0; nti < 10; ++nti)
          if (nti < ktp) v = fmaxf(v, sacc[ti][nti][r]);
        v = fmaxf(v, __shfl_xor(v, 1));
        v = fmaxf(v, __shfl_xor(v, 2));
        v = fmaxf(v, __shfl_xor(v, 4));
        v = fmaxf(v, __shfl_xor(v, 8));
        rmx[ti][r] = v;
        rsum[ti][r] = 0.f;
      }
    }
  }
  __syncthreads();  // s4: Aqu/Kt dead (S GEMM + assembly complete block-wide)

  // ---- exp, write P (wave-private rows), row sums, rstat ----
  #pragma unroll
  for (int nti = 0; nti < 10; ++nti) {
    if (nti < ktp) {
      int colv = nti * 16 + l15;
      #pragma unroll
      for (int ti = 0; ti < 2; ++ti) {
        int tt = wv + ti * 4;
        if (tt < 5) {
          #pragma unroll
          for (int r = 0; r < 4; ++r) {
            float p = __expf(sacc[ti][nti][r] - rmx[ti][r]);
            Pp[(tt * 16 + quad * 4 + r) * 168 + colv] = __float2bfloat16(p);
            rsum[ti][r] += p;
          }
        }
      }
    }
  }
  #pragma unroll
  for (int ti = 0; ti < 2; ++ti) {
    int tt = wv + ti * 4;
    if (tt < 5) {
      #pragma unroll
      for (int r = 0; r < 4; ++r) {
        float v = rsum[ti][r];
        v += __shfl_xor(v, 1);
        v += __shfl_xor(v, 2);
        v += __shfl_xor(v, 4);
        v += __shfl_xor(v, 8);
        if (l15 == 0) rstat[tt * 16 + quad * 4 + r] = 1.f / v;
      }
    }
  }
  __syncthreads();  // s5: Pp + rstat visible to all waves

  // ---- PV GEMM: O[80 x 64] = P @ V ----
  const int kmax = (ncols + 31) >> 5;
  float4v oacc[5];
  #pragma unroll
  for (int mt = 0; mt < 5; ++mt) oacc[mt] = (float4v){0.f, 0.f, 0.f, 0.f};
  const int ehi = (wv * 16 + l15) >> 3, elo = l15 & 7;
  for (int ks = 0; ks < kmax; ++ks) {
    short8v bq;
    const int blk = ehi ^ ((ks * 4 + quad) & 7);
    #pragma unroll
    for (int j = 0; j < 8; ++j)
      bq[j] = ((const short*)Vs)[(ks * 32 + quad * 8 + j) * 64 + blk * 8 + elo];
    #pragma unroll
    for (int mt = 0; mt < 5; ++mt) {
      short8v af = *(const short8v*)&Pp[(mt * 16 + l15) * 168 + ks * 32 + quad * 8];
      oacc[mt] = __builtin_amdgcn_mfma_f32_16x16x32_bf16(af, bq, oacc[mt], 0, 0, 0);
    }
  }

  // ---- epilogue (r9): bounce O through Ol (dead Eb region, disjoint from
  // Vs/Pp that PV reads) -> full-line cached writes. m==68 summary row
  // stays a direct NT store to d_out (write-only). ----
  #pragma unroll
  for (int mt = 0; mt < 5; ++mt) {
    #pragma unroll
    for (int r = 0; r < 4; ++r) {
      int m = mt * 16 + quad * 4 + r;
      float o = oacc[mt][r] * rstat[m];
      if (m < 68) {
        Ol[m * 64 + wv * 16 + l15] = __float2bfloat16(o);
      } else if (m == 68) {
        float v = fminf(fmaxf(o, -10.f), 10.f);
        size_t oi = (size_t)1088 * 8 * 512 + ((size_t)(c * 8 + b)) * 512 + h * 64 + wv * 16 + l15;
        if (obf) nt_st_bf16((bf16*)dout + oi, v);
        else     nt_st_f32((float*)dout + oi, v);
      }
    }
  }
  __syncthreads();  // s6: Ol complete
  for (int it = 0; it < 3; ++it) {
    int ci = tid + it * 256;
    if (ci < 544) {
      int m = ci >> 3, ch = ci & 7;
      int qrow = (m < 64) ? (64 + 64 * c + m) : (4 * c + (m - 64));
      uint4 v = *(const uint4*)&Ol[m * 64 + ch * 8];
      *(uint4*)(attn + ((size_t)(qrow * 8 + b)) * 512 + h * 64 + ch * 8) = v;
    }
  }
}

static inline int cdiv(int a, int b) { return (a + b - 1) / b; }

extern "C" void kernel_launch(void* const* d_in, const int* in_sizes, int n_in,
                              void* d_out, int out_size, void* d_ws, size_t ws_size,
                              hipStream_t stream) {
  const void* utter = d_in[0];
  const int*  lens  = (const int*)d_in[1];
  const void* rctx  = d_in[2];
  const void* summ  = d_in[3];
  const void* memry = d_in[4];
  // d_in[5] attention_mask: analytic, never read
  const void* pose  = d_in[6];
  const void* W_kv  = d_in[7];
  const void* b_kv  = d_in[8];
  const void* W_q   = d_in[9];
  const void* b_q   = d_in[10];
  const void* W_out = d_in[11];
  const void* b_out = d_in[12];
  const void* W_pos = d_in[13];
  const void* pbu   = d_in[14];
  const void* pbv   = d_in[15];

  const unsigned SZ_MM = MM * BB * DD;   // 61440
  const unsigned SZ_RC = RR * BB * DD;   // 262144
  const unsigned SZ_UT = UU * BB * DD;   // 4194304
  const unsigned SZ_SM = SS * BB * DD;   // 65536
  const unsigned N_XU  = SZ_MM + SZ_RC + SZ_UT + SZ_SM;  // 4583424
  const unsigned SZ_PS = 191 * DD;       // 97792

  int*  flag = (int*)d_ws;
  bf16* base = (bf16*)((char*)d_ws + 64);
  unsigned off = 0;
  bf16* XU    = base + off; unsigned o_XU    = off; off += N_XU;
  bf16* posec = base + off; unsigned o_posec = off; off += 192 * DD;
  bf16* Wcat  = base + off; unsigned o_Wcat  = off; off += (unsigned)NU * DD;
  bf16* bcat  = base + off; unsigned o_bcat  = off; off += NU;
  bf16* Woutp = base + off; unsigned o_Wout  = off; off += DD * DD;
  bf16* boutp = base + off; unsigned o_bout  = off; off += DD;
  bf16* Wposp = base + off; unsigned o_Wpos  = off; off += DD * DD;
  bf16* pbuc  = base + off; unsigned o_pbu   = off; off += DD;
  bf16* pbvc  = base + off; unsigned o_pbv   = off; off += DD;
  bf16* qkv   = base + off; off += (unsigned)(MU + 8) * NU;
  bf16* pos   = base + off; off += 192 * DD;
  bf16* attn  = base + off; off += QQ * BB * DD;

  // Fused pack: 14 segments (union X = [mem | rc | utt | summ])
  PackDesc pd;
  const void* srcs[14]  = {memry, rctx, utter, summ, pose,
                           W_q, W_kv, b_q, b_kv, W_out, b_out, W_pos, pbu, pbv};
  unsigned    soffs[14] = {0, 0, 0, 0, 896u * DD, 0, 0, 0, 0, 0, 0, 0, 0, 0};
  unsigned    doffs[14] = {o_XU, o_XU + SZ_MM, o_XU + SZ_MM + SZ_RC,
                           o_XU + SZ_MM + SZ_RC + SZ_UT, o_posec,
                           o_Wcat, o_Wcat + DD * DD, o_bcat, o_bcat + DD,
                           o_Wout, o_bout, o_Wpos, o_pbu, o_pbv};
  unsigned    ns[14]    = {SZ_MM, SZ_RC, SZ_UT, SZ_SM, SZ_PS,
                           DD * DD, 2 * DD * DD, DD, 2 * DD,
                           DD * DD, DD, DD * DD, DD, DD};
  unsigned cum = 0;
  for (int i = 0; i < 14; ++i) {
    pd.src[i] = srcs[i]; pd.srcoff[i] = soffs[i]; pd.dstoff[i] = doffs[i];
    pd.cum[i] = cum; cum += ns[i] / 8;
  }
  pd.src[14] = pbv; pd.srcoff[14] = 0; pd.dstoff[14] = o_pbv;
  pd.src[15] = pbv; pd.srcoff[15] = 0; pd.dstoff[15] = o_pbv;
  pd.cum[14] = cum; pd.cum[15] = cum; pd.cum[16] = cum;
  int nchunks = (int)cum;
  pack_all<<<dim3(cdiv(nchunks, 256)), dim3(256), 0, stream>>>(pd, base, utter, flag, nchunks);

  // fused QKV GEMM (8952 x 1536 x 512) + pos GEMM (191 x 512 x 512):
  // counted-vmcnt K-pipeline, 210 QKV blocks + 2 pos blocks, 512 threads.
  gemm8<<<dim3(212), dim3(512), 0, stream>>>(XU, Wcat, bcat, qkv, posec, Wposp, pos);

  // attention: one block per (c, b, h); writes attn rows + clipped summary rows
  attn_chunk<<<dim3(1024), dim3(256), 0, stream>>>(qkv, pos, pbuc, pbvc, lens, attn,
                                                   flag, d_out);

  // out_ru = attn[:1088] @ W_out^T + b_out (136 m-tiles * 4 n = 544 blocks)
  GemmP go{attn, Woutp, boutp, d_out, (RR + UU) * BB, DD, DD, flag};
  gemm_dual<<<dim3(4, 136), dim3(256), 0, stream>>>(go, go, 136);
}